// Round 5
// baseline (130.899 us; speedup 1.0000x reference)
//
#include <hip/hip_runtime.h>
#include <stdint.h>

typedef __attribute__((__ext_vector_type__(8))) __bf16 bf16x8;
typedef __attribute__((__ext_vector_type__(4))) float  f32x4;

// ---- workspace layout (bytes) ----
#define XT_OFF    0ul          // 16*64*64*256 bf16 = 33,554,432
#define WT_OFF    33554432ul   // 36*16384 bf16     =  1,179,648  [tap][s][co][ci64]
#define BEFF_OFF  34734080ul   // 256 f32
#define ZERO_OFF  34737152ul   // 256 B zeros
#define STATS_OFF 34737408ul   // 512 f32 (sum, sumsq per channel)

__device__ inline void gload_lds16(const void* g, void* l) {
  __builtin_amdgcn_global_load_lds((const __attribute__((address_space(1))) void*)g,
                                   (__attribute__((address_space(3))) void*)l,
                                   16, 0, 0);
}

// K1: Wt[(tap*4+s)*16384 + co*64 + cis] = alpha/16 * sum_{r,o} w[r*256+co][o*256+ci][tap]
__global__ void k_wred(const float* __restrict__ w, const float* __restrict__ bias,
                       const float* __restrict__ alpha_p, __bf16* __restrict__ Wt,
                       float* __restrict__ beff, float* __restrict__ zerob,
                       float* __restrict__ statsG) {
  const int co = blockIdx.x;    // 256
  const int ci = threadIdx.x;   // 256
  float a[9];
#pragma unroll
  for (int t = 0; t < 9; ++t) a[t] = 0.f;
#pragma unroll
  for (int r = 0; r < 2; ++r)
#pragma unroll
    for (int o = 0; o < 8; ++o) {
      const float* p = w + ((size_t)(r * 256 + co) * 2048 + (size_t)(o * 256 + ci)) * 9;
#pragma unroll
      for (int t = 0; t < 9; ++t) a[t] += p[t];
    }
  const float sc = alpha_p[0] * 0.0625f;      // alpha / (NORI*NROT)
  const int s = ci >> 6, cis = ci & 63;
#pragma unroll
  for (int t = 0; t < 9; ++t)
    Wt[(size_t)(t * 4 + s) * 16384 + co * 64 + cis] = (__bf16)(a[t] * sc);
  if (ci == 0) beff[co] = (bias[co] + bias[256 + co]) * 8.0f * sc;
  if (blockIdx.x == 0) {
    statsG[ci] = 0.f; statsG[256 + ci] = 0.f;
    if (ci < 64) zerob[ci] = 0.f;
  }
}

// K1b: x[b][ci][h][w] f32 -> xT[b][h][w][ci] bf16  (LDS-tiled transpose)
__global__ void k_xpose(const float* __restrict__ x, __bf16* __restrict__ xT) {
  __shared__ __bf16 lds[64 * 258];
  int bh = blockIdx.x;          // 16*64
  int b = bh >> 6, h = bh & 63;
  int t = threadIdx.x;          // 256
  int w = t & 63, cg = t >> 6;
  const float* xb = x + ((size_t)b * 16384 + h) * 64;   // + ci*4096 + w
#pragma unroll 4
  for (int cb = 0; cb < 256; cb += 4) {
    int ci = cb + cg;
    lds[w * 258 + ci] = (__bf16)xb[(size_t)ci * 4096 + w];
  }
  __syncthreads();
  const uint32_t* l32 = (const uint32_t*)lds;
  uint32_t* o32 = (uint32_t*)(xT + ((size_t)b * 64 + h) * 64 * 256);
  int c2 = t & 127, wg = t >> 7;              // 2 w per iter
  for (int w0 = 0; w0 < 64; w0 += 2) {
    int ww = w0 + wg;
    o32[ww * 128 + c2] = l32[ww * 129 + c2];
  }
}

// K2: implicit-GEMM conv + residual + fused BN stats.
// 256 blocks (1/CU), 512 threads = 8 waves (2m x 4n), wave tile 128x64.
// 36 phases = s(4 ci64) x tap(9), K=64/phase.
// Pipeline: 3 B buffers, depth-2 prefetch. Per phase p:
//   vmcnt(4) [own B(p) landed] ; s_barrier [all waves' B(p) landed + all done
//   reading buf[(p+2)%3]] ; issue stage B(p+2) ; MFMA(p).
// Loads for B(p+1), B(p+2) stay in flight across the barrier (T4).
// A slab single-buffered, restaged at s boundaries with one extra vmcnt(4).
#define A_BYTES 51200            // 50 chunks * 1024 (396 pos * 128B, padded)
#define B_BYTES 32768

__global__ __launch_bounds__(512) void k_conv(
    const float* __restrict__ x, const __bf16* __restrict__ xT,
    const __bf16* __restrict__ Wt, const float* __restrict__ beff,
    const __bf16* __restrict__ zerob, float* __restrict__ out,
    float* __restrict__ statsG)
{
  __shared__ __align__(16) char lds[A_BYTES + 3 * B_BYTES];   // 149504 B
  const int bb   = blockIdx.x >> 4;
  const int ho0  = (blockIdx.x & 15) << 2;   // 4 output rows per block
  const int tid  = threadIdx.x;
  const int lane = tid & 63;
  const int wid  = tid >> 6;                 // 8 waves: 2 (m) x 4 (co)
  const int wr   = wid >> 2;                 // m half: rows ho0+wr*2+{0,1}
  const int wc   = wid & 3;                  // co quarter (64)

  f32x4 acc[8][4];
#pragma unroll
  for (int i = 0; i < 8; ++i)
#pragma unroll
    for (int j = 0; j < 4; ++j)
#pragma unroll
      for (int r = 0; r < 4; ++r) acc[i][j][r] = 0.f;

  const char* zb = (const char*)zerob;

  // hoisted B ds_read byte offsets (constant across phases)
  int boff[4][2];
#pragma unroll
  for (int j = 0; j < 4; ++j)
#pragma unroll
    for (int kk = 0; kk < 2; ++kk) {
      const int co     = (wc << 6) + (j << 4) + (lane & 15);
      const int ci_off = (kk << 5) + ((lane >> 4) << 3);
      boff[j][kk] = ((co << 7) + (ci_off << 1)) ^ ((co & 7) << 4);
    }
  // B stage per-lane source offset within a 32KB phase-tile:
  // instr t covers co = t*8 + (lane>>3); src slot = (lane&7)^(co&7)
  const int bl = lane >> 3;
  const int bsrcLane = (bl << 7) + (((lane & 7) ^ (bl & 7)) << 4);

  // ---- stage A slab for ci-block s: slab[r=6][c=66][ci=64] bf16, 128B/pos.
  // 16B-slot swizzle: phys_slot = logical_slot ^ (pos&7); linear LDS dest +
  // inverse-swizzled global source (G21).
  auto stageA = [&](int s) {
    const int ci0 = s << 6;
    for (int t = wid; t < 50; t += 8) {
      const int ch = (t << 3) + (lane >> 3);   // pos = r*66+c, 0..399
      const int r  = ch / 66;
      const int c  = ch - r * 66;
      const int ir = ho0 - 1 + r;              // image row
      const int ic = c - 1;                    // image col
      const int k  = (lane & 7) ^ (ch & 7);    // logical 16B slot (8 ci elems)
      const char* src;
      if (ch < 396 && ir >= 0 && ir < 64 && ic >= 0 && ic < 64)
        src = (const char*)(xT + ((((size_t)bb << 6) + ir) * 64 + ic) * 256 + ci0 + (k << 3));
      else
        src = zb + (k << 4);
      gload_lds16(src, lds + (t << 10));
    }
  };

  // ---- stage B tile for flat phase ph into buf[ph%3]: [co=256][ci=64] bf16.
  // Wt layout [tap][s][co][ci] -> tile source is one contiguous 32KB block.
  auto stageB = [&](int ph) {
    char* buf = lds + A_BYTES + (ph % 3) * B_BYTES;
    const int tap = ph / 4 - (ph / 36) * 9;    // ph = s*9+tap; recompute below
    (void)tap;
    const int s2 = ph / 9, tp = ph - s2 * 9;
    const char* wsrc = (const char*)Wt + ((size_t)(tp * 4 + s2) << 15) + bsrcLane;
#pragma unroll
    for (int it = 0; it < 4; ++it) {
      const int t = wid + (it << 3);           // 0..31
      gload_lds16(wsrc + (t << 10), buf + (t << 10));
    }
  };

  // prologue: A(0), B(0), B(1) in flight; drain A(0)+B(0), keep B(1)
  stageA(0);
  stageB(0);
  stageB(1);
  asm volatile("s_waitcnt vmcnt(4)" ::: "memory");
  __builtin_amdgcn_s_barrier();

  int s = 0, tap = 0;
  for (int p = 0; p < 36; ++p) {
    if (p > 0) {
      if (p == 35) asm volatile("s_waitcnt vmcnt(0)" ::: "memory");
      else         asm volatile("s_waitcnt vmcnt(4)" ::: "memory");
      __builtin_amdgcn_s_barrier();
    }
    const bool bnd = (tap == 0) && (p > 0);    // s-boundary: restage A
    if (bnd) stageA(s);
    if (p + 2 < 36) stageB(p + 2);
    if (bnd) asm volatile("s_waitcnt vmcnt(4)" ::: "memory");  // A landed; B(p+2) in flight

    const int dh = (tap >= 6) ? 2 : (tap >= 3 ? 1 : 0);
    const int dw = tap - dh * 3;
    const char* Bb = lds + A_BYTES + (p % 3) * B_BYTES;
    __builtin_amdgcn_s_setprio(1);
#pragma unroll
    for (int kk = 0; kk < 2; ++kk) {
      const int ci_off = (kk << 5) + ((lane >> 4) << 3);
      bf16x8 av[8];
#pragma unroll
      for (int i = 0; i < 8; ++i) {
        const int pos = ((wr << 1) + (i >> 2) + dh) * 66 + ((i & 3) << 4) + (lane & 15) + dw;
        const int off = ((pos << 7) + (ci_off << 1)) ^ ((pos & 7) << 4);
        av[i] = *(const bf16x8*)(lds + off);
      }
#pragma unroll
      for (int j = 0; j < 4; ++j) {
        const bf16x8 bv = *(const bf16x8*)(Bb + boff[j][kk]);
#pragma unroll
        for (int i = 0; i < 8; ++i)
          acc[i][j] = __builtin_amdgcn_mfma_f32_16x16x32_bf16(av[i], bv, acc[i][j], 0, 0, 0);
      }
    }
    __builtin_amdgcn_s_setprio(0);

    if (++tap == 9) { tap = 0; ++s; }
  }

  // ---- epilogue: per-wave LDS transpose (coalesced IO) + fused BN stats
  __syncthreads();
  float* sw    = (float*)lds + wid * 2064;     // 16 co x 129 m floats per wave
  float* lstat = (float*)(lds + 131072);       // 512 floats
  if (tid < 512) lstat[tid] = 0.f;
  __syncthreads();

  const int cl = lane & 15, ch4 = (lane >> 4) << 2;
  const int cc2 = lane >> 2, q = lane & 3;     // stats-reduction roles
#pragma unroll
  for (int j = 0; j < 4; ++j) {
    asm volatile("s_waitcnt lgkmcnt(0)" ::: "memory");
#pragma unroll
    for (int i = 0; i < 8; ++i)
#pragma unroll
      for (int r = 0; r < 4; ++r)
        sw[cl * 129 + (i << 4) + ch4 + r] = acc[i][j][r];
    asm volatile("s_waitcnt lgkmcnt(0)" ::: "memory");
    for (int cc = 0; cc < 16; ++cc) {
      const int co = (wc << 6) + (j << 4) + cc;
      const float be = beff[co];
#pragma unroll
      for (int half = 0; half < 2; ++half) {
        const float conv = sw[cc * 129 + (half << 6) + lane];
        const int ho = ho0 + (wr << 1) + half;
        const size_t oi = ((((size_t)bb << 8) + (size_t)co) << 12) + (ho << 6) + lane;
        const float v = x[oi] + conv + be;
        out[oi] = v;
        sw[cc * 129 + (half << 6) + lane] = v;   // same addr per lane: no race
      }
    }
    asm volatile("s_waitcnt lgkmcnt(0)" ::: "memory");
    // per-thread partial over 32 m-values of one co, then 2-level shfl (q)
    float r1 = 0.f, r2 = 0.f;
#pragma unroll
    for (int k = 0; k < 32; ++k) {
      const float vv = sw[cc2 * 129 + (q << 5) + k];
      r1 += vv; r2 += vv * vv;
    }
    r1 += __shfl_xor(r1, 1); r2 += __shfl_xor(r2, 1);
    r1 += __shfl_xor(r1, 2); r2 += __shfl_xor(r2, 2);
    if (q == 0) {
      const int co = (wc << 6) + (j << 4) + cc2;
      atomicAdd(&lstat[co], r1);
      atomicAdd(&lstat[256 + co], r2);
    }
    asm volatile("s_waitcnt lgkmcnt(0)" ::: "memory");  // reads done before next j overwrites
  }
  __syncthreads();
  if (tid < 512) atomicAdd(&statsG[tid], lstat[tid]);
}

// K3: BN finalize (inline) + apply
__global__ void k_apply(float* __restrict__ out, const float* __restrict__ statsG,
                        const float* __restrict__ gamma, const float* __restrict__ beta) {
  size_t i = (size_t)blockIdx.x * 256 + threadIdx.x;   // float4 index
  int co = (int)((i >> 10) & 255);
  const float mean = statsG[co] * (1.f / 65536.f);
  const float var  = statsG[256 + co] * (1.f / 65536.f) - mean * mean;
  const float inv  = rsqrtf(var + 1e-5f);
  const float sc   = gamma[co] * inv;
  const float sh   = beta[co] - mean * sc;
  float4* p = (float4*)out;
  float4 v = p[i];
  v.x = v.x * sc + sh; v.y = v.y * sc + sh; v.z = v.z * sc + sh; v.w = v.w * sc + sh;
  p[i] = v;
}

extern "C" void kernel_launch(void* const* d_in, const int* in_sizes, int n_in,
                              void* d_out, int out_size, void* d_ws, size_t ws_size,
                              hipStream_t stream) {
  const float* x     = (const float*)d_in[0];
  const float* wall  = (const float*)d_in[1];
  const float* bias  = (const float*)d_in[2];
  const float* alpha = (const float*)d_in[3];
  const float* gamma = (const float*)d_in[4];
  const float* beta  = (const float*)d_in[5];
  float* out = (float*)d_out;

  char* ws = (char*)d_ws;
  __bf16* xT     = (__bf16*)(ws + XT_OFF);
  __bf16* Wt     = (__bf16*)(ws + WT_OFF);
  float*  beff   = (float*)(ws + BEFF_OFF);
  float*  zerob  = (float*)(ws + ZERO_OFF);
  float*  statsG = (float*)(ws + STATS_OFF);

  k_wred<<<256, 256, 0, stream>>>(wall, bias, alpha, Wt, beff, zerob, statsG);
  k_xpose<<<1024, 256, 0, stream>>>(x, xT);
  k_conv<<<256, 512, 0, stream>>>(x, xT, Wt, beff, (const __bf16*)zerob, out, statsG);
  k_apply<<<16384, 256, 0, stream>>>(out, statsG, gamma, beta);
}

// Round 6
// 129.685 us; speedup vs baseline: 1.0094x; 1.0094x over previous
//
#include <hip/hip_runtime.h>
#include <stdint.h>

typedef __attribute__((__ext_vector_type__(8))) __bf16 bf16x8;
typedef __attribute__((__ext_vector_type__(4))) float  f32x4;

// ---- workspace layout (bytes) ----
#define XT_OFF    0ul          // 16*64*64*256 bf16 = 33,554,432
#define WT_OFF    33554432ul   // 36*16384 bf16     =  1,179,648  [tap][s][co][ci64]
#define BEFF_OFF  34734080ul   // 256 f32
#define ZERO_OFF  34737152ul   // 256 B zeros
#define STATS_OFF 34737408ul   // 512 f32 (sum, sumsq per channel)

__device__ inline void gload_lds16(const void* g, void* l) {
  __builtin_amdgcn_global_load_lds((const __attribute__((address_space(1))) void*)g,
                                   (__attribute__((address_space(3))) void*)l,
                                   16, 0, 0);
}

// K1: Wt[(tap*4+s)*16384 + co*64 + cis] = alpha/16 * sum_{r,o} w[r*256+co][o*256+ci][tap]
__global__ void k_wred(const float* __restrict__ w, const float* __restrict__ bias,
                       const float* __restrict__ alpha_p, __bf16* __restrict__ Wt,
                       float* __restrict__ beff, float* __restrict__ zerob,
                       float* __restrict__ statsG) {
  const int co = blockIdx.x;    // 256
  const int ci = threadIdx.x;   // 256
  float a[9];
#pragma unroll
  for (int t = 0; t < 9; ++t) a[t] = 0.f;
#pragma unroll
  for (int r = 0; r < 2; ++r)
#pragma unroll
    for (int o = 0; o < 8; ++o) {
      const float* p = w + ((size_t)(r * 256 + co) * 2048 + (size_t)(o * 256 + ci)) * 9;
#pragma unroll
      for (int t = 0; t < 9; ++t) a[t] += p[t];
    }
  const float sc = alpha_p[0] * 0.0625f;      // alpha / (NORI*NROT)
  const int s = ci >> 6, cis = ci & 63;
#pragma unroll
  for (int t = 0; t < 9; ++t)
    Wt[(size_t)(t * 4 + s) * 16384 + co * 64 + cis] = (__bf16)(a[t] * sc);
  if (ci == 0) beff[co] = (bias[co] + bias[256 + co]) * 8.0f * sc;
  if (blockIdx.x == 0) {
    statsG[ci] = 0.f; statsG[256 + ci] = 0.f;
    if (ci < 64) zerob[ci] = 0.f;
  }
}

// K1b: x[b][ci][h][w] f32 -> xT[b][h][w][ci] bf16  (LDS-tiled transpose)
__global__ void k_xpose(const float* __restrict__ x, __bf16* __restrict__ xT) {
  __shared__ __bf16 lds[64 * 258];
  int bh = blockIdx.x;          // 16*64
  int b = bh >> 6, h = bh & 63;
  int t = threadIdx.x;          // 256
  int w = t & 63, cg = t >> 6;
  const float* xb = x + ((size_t)b * 16384 + h) * 64;   // + ci*4096 + w
#pragma unroll 4
  for (int cb = 0; cb < 256; cb += 4) {
    int ci = cb + cg;
    lds[w * 258 + ci] = (__bf16)xb[(size_t)ci * 4096 + w];
  }
  __syncthreads();
  const uint32_t* l32 = (const uint32_t*)lds;
  uint32_t* o32 = (uint32_t*)(xT + ((size_t)b * 64 + h) * 64 * 256);
  int c2 = t & 127, wg = t >> 7;              // 2 w per iter
  for (int w0 = 0; w0 < 64; w0 += 2) {
    int ww = w0 + wg;
    o32[ww * 128 + c2] = l32[ww * 129 + c2];
  }
}

// K2: implicit-GEMM conv + residual + fused BN stats.
// 256 blocks (1/CU), 512 threads = 8 waves (2m x 4n), wave tile 128x64.
// 36 phases = s(4 ci64) x tap(9), K=64/phase.
// Staging: 3 B buffers, depth-2 prefetch, counted vmcnt(4) per phase (T4).
// Compute: 4 groups x 16 MFMA, ds_reads issued one group ahead (read-ahead
// software pipeline; compiler emits counted lgkmcnt per consumer).
#define A_BYTES 51200            // 50 chunks * 1024 (396 pos * 128B, padded)
#define B_BYTES 32768

#define MFMA16(RH, AV, BV)                                                      \
  _Pragma("unroll")                                                             \
  for (int j = 0; j < 4; ++j) {                                                 \
    _Pragma("unroll")                                                           \
    for (int q = 0; q < 4; ++q)                                                 \
      acc[(RH) * 4 + q][j] =                                                    \
        __builtin_amdgcn_mfma_f32_16x16x32_bf16(AV[q], BV[j],                   \
                                                acc[(RH) * 4 + q][j], 0, 0, 0); \
  }

__global__ __launch_bounds__(512) void k_conv(
    const float* __restrict__ x, const __bf16* __restrict__ xT,
    const __bf16* __restrict__ Wt, const float* __restrict__ beff,
    const __bf16* __restrict__ zerob, float* __restrict__ out,
    float* __restrict__ statsG)
{
  __shared__ __align__(16) char lds[A_BYTES + 3 * B_BYTES];   // 149504 B
  const int bb   = blockIdx.x >> 4;
  const int ho0  = (blockIdx.x & 15) << 2;   // 4 output rows per block
  const int tid  = threadIdx.x;
  const int lane = tid & 63;
  const int wid  = tid >> 6;                 // 8 waves: 2 (m) x 4 (co)
  const int wr   = wid >> 2;                 // m half: rows ho0+wr*2+{0,1}
  const int wc   = wid & 3;                  // co quarter (64)
  const int l15  = lane & 15;

  f32x4 acc[8][4];
#pragma unroll
  for (int i = 0; i < 8; ++i)
#pragma unroll
    for (int j = 0; j < 4; ++j)
#pragma unroll
      for (int r = 0; r < 4; ++r) acc[i][j][r] = 0.f;

  const char* zb = (const char*)zerob;

  // B ds_read bases (constant): co0 = wc*64 + l15; +j*16 co keeps co&7.
  const int co0 = (wc << 6) + l15;
  const int bb0 = (((co0 << 7) + ((lane >> 4) << 4)) ^ ((co0 & 7) << 4));
  const int bb1 = (((co0 << 7) + ((lane >> 4) << 4) + 64) ^ ((co0 & 7) << 4));
  // B stage per-lane source offset within a 32KB phase-tile
  const int bl = lane >> 3;
  const int bsrcLane = (bl << 7) + (((lane & 7) ^ (bl & 7)) << 4);

  // ---- stage A slab for ci-block s: slab[r=6][c=66][ci=64] bf16, 128B/pos.
  // 16B-slot swizzle: phys_slot = logical_slot ^ (pos&7); linear LDS dest +
  // inverse-swizzled global source (G21).
  auto stageA = [&](int s) {
    const int ci0 = s << 6;
    for (int t = wid; t < 50; t += 8) {
      const int ch = (t << 3) + (lane >> 3);   // pos = r*66+c, 0..399
      const int r  = ch / 66;
      const int c  = ch - r * 66;
      const int ir = ho0 - 1 + r;              // image row
      const int ic = c - 1;                    // image col
      const int k  = (lane & 7) ^ (ch & 7);    // logical 16B slot (8 ci elems)
      const char* src;
      if (ch < 396 && ir >= 0 && ir < 64 && ic >= 0 && ic < 64)
        src = (const char*)(xT + ((((size_t)bb << 6) + ir) * 64 + ic) * 256 + ci0 + (k << 3));
      else
        src = zb + (k << 4);
      gload_lds16(src, lds + (t << 10));
    }
  };

  // ---- stage B tile for flat phase ph into buffer bi: [co=256][ci=64] bf16.
  // Wt layout [tap][s][co][ci] -> one contiguous 32KB source block per phase.
  auto stageB = [&](int ph, int bi) {
    char* buf = lds + A_BYTES + bi * B_BYTES;
    const int s2 = ph / 9, tp = ph - s2 * 9;
    const char* wsrc = (const char*)Wt + ((size_t)(tp * 4 + s2) << 15) + bsrcLane;
#pragma unroll
    for (int it = 0; it < 4; ++it) {
      const int t = wid + (it << 3);           // 0..31
      gload_lds16(wsrc + (t << 10), buf + (t << 10));
    }
  };

  // prologue: A(0), B(0), B(1) in flight; drain A(0)+B(0), keep B(1)
  stageA(0);
  stageB(0, 0);
  stageB(1, 1);
  asm volatile("s_waitcnt vmcnt(4)" ::: "memory");
  __builtin_amdgcn_s_barrier();

  int s = 0, tap = 0, bcur = 0;
  for (int p = 0; p < 36; ++p) {
    if (p > 0) {
      if (p == 35) asm volatile("s_waitcnt vmcnt(0)" ::: "memory");
      else         asm volatile("s_waitcnt vmcnt(4)" ::: "memory");
      __builtin_amdgcn_s_barrier();
    }
    const bool bnd = (tap == 0) && (p > 0);    // s-boundary: restage A
    if (bnd) stageA(s);
    if (p + 2 < 36) {
      int bnx = bcur + 2; if (bnx >= 3) bnx -= 3;
      stageB(p + 2, bnx);
    }
    if (bnd) asm volatile("s_waitcnt vmcnt(4)" ::: "memory");  // A landed

    const int dh = (tap >= 6) ? 2 : (tap >= 3 ? 1 : 0);
    const int dw = tap - dh * 3;
    const char* Bb = lds + A_BYTES + bcur * B_BYTES;
    // A ds_read bases: pos = prow + q*16 keeps pos&7 -> q goes to imm offset
    const int pr0  = ((wr << 1) + dh) * 66 + l15 + dw;
    const int pr1  = pr0 + 66;
    const int cib  = (lane >> 4) << 4;         // kk0 ci bytes; kk1 = +64
    const int ab00 = (((pr0 << 7) + cib) ^ ((pr0 & 7) << 4));
    const int ab01 = (((pr1 << 7) + cib) ^ ((pr1 & 7) << 4));
    const int ab10 = (((pr0 << 7) + cib + 64) ^ ((pr0 & 7) << 4));
    const int ab11 = (((pr1 << 7) + cib + 64) ^ ((pr1 & 7) << 4));

    bf16x8 bv0[4], bv1[4], a0[4], a1[4], a2[4], a3[4];
#pragma unroll
    for (int j = 0; j < 4; ++j) bv0[j] = *(const bf16x8*)(Bb + bb0 + (j << 11));
#pragma unroll
    for (int j = 0; j < 4; ++j) bv1[j] = *(const bf16x8*)(Bb + bb1 + (j << 11));
#pragma unroll
    for (int q = 0; q < 4; ++q) a0[q] = *(const bf16x8*)(lds + ab00 + (q << 11));
#pragma unroll
    for (int q = 0; q < 4; ++q) a1[q] = *(const bf16x8*)(lds + ab01 + (q << 11));

    __builtin_amdgcn_s_setprio(1);
    MFMA16(0, a0, bv0);
    __builtin_amdgcn_s_setprio(0);
#pragma unroll
    for (int q = 0; q < 4; ++q) a2[q] = *(const bf16x8*)(lds + ab10 + (q << 11));
    __builtin_amdgcn_s_setprio(1);
    MFMA16(1, a1, bv0);
    __builtin_amdgcn_s_setprio(0);
#pragma unroll
    for (int q = 0; q < 4; ++q) a3[q] = *(const bf16x8*)(lds + ab11 + (q << 11));
    __builtin_amdgcn_s_setprio(1);
    MFMA16(0, a2, bv1);
    MFMA16(1, a3, bv1);
    __builtin_amdgcn_s_setprio(0);

    if (++tap == 9) { tap = 0; ++s; }
    if (++bcur == 3) bcur = 0;
  }

  // ---- epilogue: per-wave LDS transpose (coalesced IO) + fused BN stats
  __syncthreads();
  float* sw    = (float*)lds + wid * 2064;     // 16 co x 129 m floats per wave
  float* lstat = (float*)(lds + 131072);       // 512 floats
  if (tid < 512) lstat[tid] = 0.f;
  __syncthreads();

  const int cl = lane & 15, ch4 = (lane >> 4) << 2;
  const int cc2 = lane >> 2, q2 = lane & 3;    // stats-reduction roles
#pragma unroll
  for (int j = 0; j < 4; ++j) {
#pragma unroll
    for (int i = 0; i < 8; ++i)
#pragma unroll
      for (int r = 0; r < 4; ++r)
        sw[cl * 129 + (i << 4) + ch4 + r] = acc[i][j][r];
    for (int cc = 0; cc < 16; ++cc) {
      const int co = (wc << 6) + (j << 4) + cc;
      const float be = beff[co];
#pragma unroll
      for (int half = 0; half < 2; ++half) {
        const float conv = sw[cc * 129 + (half << 6) + lane];
        const int ho = ho0 + (wr << 1) + half;
        const size_t oi = ((((size_t)bb << 8) + (size_t)co) << 12) + (ho << 6) + lane;
        const float v = x[oi] + conv + be;
        out[oi] = v;
        sw[cc * 129 + (half << 6) + lane] = v;   // same addr per lane: no race
      }
    }
    // per-thread partial over 32 m-values of one co, then 2-level shfl
    float r1 = 0.f, r2 = 0.f;
#pragma unroll
    for (int k = 0; k < 32; ++k) {
      const float vv = sw[cc2 * 129 + (q2 << 5) + k];
      r1 += vv; r2 += vv * vv;
    }
    r1 += __shfl_xor(r1, 1); r2 += __shfl_xor(r2, 1);
    r1 += __shfl_xor(r1, 2); r2 += __shfl_xor(r2, 2);
    if (q2 == 0) {
      const int co = (wc << 6) + (j << 4) + cc2;
      atomicAdd(&lstat[co], r1);
      atomicAdd(&lstat[256 + co], r2);
    }
    __syncthreads();                             // sw reuse fence across waves' j
  }
  if (tid < 512) atomicAdd(&statsG[tid], lstat[tid]);
}

// K3: BN finalize (inline) + apply
__global__ void k_apply(float* __restrict__ out, const float* __restrict__ statsG,
                        const float* __restrict__ gamma, const float* __restrict__ beta) {
  size_t i = (size_t)blockIdx.x * 256 + threadIdx.x;   // float4 index
  int co = (int)((i >> 10) & 255);
  const float mean = statsG[co] * (1.f / 65536.f);
  const float var  = statsG[256 + co] * (1.f / 65536.f) - mean * mean;
  const float inv  = rsqrtf(var + 1e-5f);
  const float sc   = gamma[co] * inv;
  const float sh   = beta[co] - mean * sc;
  float4* p = (float4*)out;
  float4 v = p[i];
  v.x = v.x * sc + sh; v.y = v.y * sc + sh; v.z = v.z * sc + sh; v.w = v.w * sc + sh;
  p[i] = v;
}

extern "C" void kernel_launch(void* const* d_in, const int* in_sizes, int n_in,
                              void* d_out, int out_size, void* d_ws, size_t ws_size,
                              hipStream_t stream) {
  const float* x     = (const float*)d_in[0];
  const float* wall  = (const float*)d_in[1];
  const float* bias  = (const float*)d_in[2];
  const float* alpha = (const float*)d_in[3];
  const float* gamma = (const float*)d_in[4];
  const float* beta  = (const float*)d_in[5];
  float* out = (float*)d_out;

  char* ws = (char*)d_ws;
  __bf16* xT     = (__bf16*)(ws + XT_OFF);
  __bf16* Wt     = (__bf16*)(ws + WT_OFF);
  float*  beff   = (float*)(ws + BEFF_OFF);
  float*  zerob  = (float*)(ws + ZERO_OFF);
  float*  statsG = (float*)(ws + STATS_OFF);

  k_wred<<<256, 256, 0, stream>>>(wall, bias, alpha, Wt, beff, zerob, statsG);
  k_xpose<<<1024, 256, 0, stream>>>(x, xT);
  k_conv<<<256, 512, 0, stream>>>(x, xT, Wt, beff, (const __bf16*)zerob, out, statsG);
  k_apply<<<16384, 256, 0, stream>>>(out, statsG, gamma, beta);
}